// Round 1
// baseline (177.647 us; speedup 1.0000x reference)
//
#include <hip/hip_runtime.h>

#define MAX_POINTS 32
#define C_OUT 64
#define EPS 1e-5f

// ws layout (floats): [0:64) S, [64:128) SS, [128] valid count
// All zeroed by hipMemsetAsync before stats kernel.

__global__ __launch_bounds__(256) void vfe_stats(
    const float* __restrict__ x, const int* __restrict__ vnp,
    const float* __restrict__ W, const float* __restrict__ b,
    float* __restrict__ ws, int M)
{
    const int lane = threadIdx.x & 63;          // channel
    const int wid  = threadIdx.x >> 6;          // wave in block
    const int gw   = blockIdx.x * 4 + wid;      // global wave id
    const int nw   = gridDim.x * 4;             // total waves

    const float4 w4  = ((const float4*)W)[lane];  // W[o][0..3]
    const float bias = b[lane];

    float s = 0.f, ss = 0.f, cnt = 0.f;
    for (int m = gw; m < M; m += nw) {
        const int n = vnp[m];                    // wave-uniform
        const float4* xp = (const float4*)x + m * MAX_POINTS;
        for (int p = 0; p < n; ++p) {            // uniform trip count: no divergence
            const float4 q = xp[p];              // same addr across wave -> 1 txn
            const float h = fmaf(q.x, w4.x, fmaf(q.y, w4.y,
                            fmaf(q.z, w4.z, fmaf(q.w, w4.w, bias))));
            s  += h;
            ss  = fmaf(h, h, ss);
        }
        cnt += (float)n;
    }

    // block reduce (4 waves -> 1), then 2 atomics per channel per block
    __shared__ float red[2][256];
    __shared__ float credu[4];
    red[0][threadIdx.x] = s;
    red[1][threadIdx.x] = ss;
    if (lane == 0) credu[wid] = cnt;             // cnt is wave-uniform
    __syncthreads();
    if (threadIdx.x < 64) {
        const int t = threadIdx.x;
        const float S  = red[0][t] + red[0][t+64] + red[0][t+128] + red[0][t+192];
        const float SS = red[1][t] + red[1][t+64] + red[1][t+128] + red[1][t+192];
        atomicAdd(&ws[t],      S);
        atomicAdd(&ws[64 + t], SS);
        if (t == 0)
            atomicAdd(&ws[128], credu[0] + credu[1] + credu[2] + credu[3]);
    }
}

__global__ __launch_bounds__(256) void vfe_out(
    const float* __restrict__ x, const int* __restrict__ vnp,
    const float* __restrict__ W, const float* __restrict__ b,
    const float* __restrict__ gamma, const float* __restrict__ beta,
    const float* __restrict__ ws, float* __restrict__ out, int M)
{
    const int lane = threadIdx.x & 63;          // channel
    const int wid  = threadIdx.x >> 6;
    const int gw   = blockIdx.x * 4 + wid;
    const int nw   = gridDim.x * 4;

    const float4 w4  = ((const float4*)W)[lane];
    const float bias = b[lane];

    // finalize BN affine per lane: hn = h*A + B for valid slots
    const float nv  = fmaxf(ws[128], 1.0f);
    const float mu  = ws[lane] / nv;
    const float var = ws[64 + lane] / nv - mu * mu;
    const float inv = rsqrtf(var + EPS);
    const float A   = gamma[lane] * inv;
    const float B   = fmaf(-mu, A, beta[lane]);

    for (int m = gw; m < M; m += nw) {
        const int n = vnp[m];                    // wave-uniform
        const float4* xp = (const float4*)x + m * MAX_POINTS;
        float acc = 0.f;
        for (int p = 0; p < n; ++p) {
            const float4 q = xp[p];
            const float h = fmaf(q.x, w4.x, fmaf(q.y, w4.y,
                            fmaf(q.z, w4.z, fmaf(q.w, w4.w, bias))));
            const float v = fmaf(h, A, B);
            acc += fmaxf(v, 0.f);
        }
        out[m * C_OUT + lane] = acc / fmaxf((float)n, 1.0f);  // coalesced store
    }
}

extern "C" void kernel_launch(void* const* d_in, const int* in_sizes, int n_in,
                              void* d_out, int out_size, void* d_ws, size_t ws_size,
                              hipStream_t stream) {
    const float* x     = (const float*)d_in[0];
    const int*   vnp   = (const int*)  d_in[1];
    const float* W     = (const float*)d_in[2];
    const float* b     = (const float*)d_in[3];
    const float* gamma = (const float*)d_in[4];
    const float* beta  = (const float*)d_in[5];
    float* out = (float*)d_out;
    float* ws  = (float*)d_ws;
    const int M = in_sizes[1];                  // 40000 voxels

    hipMemsetAsync(d_ws, 0, 129 * sizeof(float), stream);
    vfe_stats<<<1024, 256, 0, stream>>>(x, vnp, W, b, ws, M);
    vfe_out<<<2500, 256, 0, stream>>>(x, vnp, W, b, gamma, beta, ws, out, M);
}

// Round 2
// 105.992 us; speedup vs baseline: 1.6760x; 1.6760x over previous
//
#include <hip/hip_runtime.h>

#define MAX_POINTS 32
#define C_OUT 64
#define EPS 1e-5f

// ws layout (floats):
//  [0..3]  : sum x  (sx, sy, sz, sw)
//  [4..13] : second moments xx,xy,xz,xw,yy,yz,yw,zz,zw,ww
//  [14]    : valid-point count
#define NMOM 15

// ---------------- Pass 1: 15-scalar moment reduction (coalesced streaming) ---
__global__ __launch_bounds__(256) void vfe_stats(
    const float* __restrict__ x, const int* __restrict__ vnp,
    float* __restrict__ ws, int M)
{
    const int tid    = blockIdx.x * 256 + threadIdx.x;
    const int stride = gridDim.x * 256;
    const int total  = M * MAX_POINTS;            // flat float4 slots

    float a[NMOM];
    #pragma unroll
    for (int i = 0; i < NMOM; ++i) a[i] = 0.f;

    const float4* __restrict__ xq = (const float4*)x;
    for (int i = tid; i < total; i += stride) {
        const int m = i >> 5;
        const int p = i & 31;
        const int n = vnp[m];                     // L1/L2-cached
        const bool valid = p < n;
        float4 q = make_float4(0.f, 0.f, 0.f, 0.f);
        if (valid) q = xq[i];                     // coalesced, exec-masked
        a[0] += q.x; a[1] += q.y; a[2] += q.z; a[3] += q.w;
        a[4]  = fmaf(q.x, q.x, a[4]);
        a[5]  = fmaf(q.x, q.y, a[5]);
        a[6]  = fmaf(q.x, q.z, a[6]);
        a[7]  = fmaf(q.x, q.w, a[7]);
        a[8]  = fmaf(q.y, q.y, a[8]);
        a[9]  = fmaf(q.y, q.z, a[9]);
        a[10] = fmaf(q.y, q.w, a[10]);
        a[11] = fmaf(q.z, q.z, a[11]);
        a[12] = fmaf(q.z, q.w, a[12]);
        a[13] = fmaf(q.w, q.w, a[13]);
        a[14] += valid ? 1.f : 0.f;
    }

    // wave reduce (64 lanes)
    #pragma unroll
    for (int i = 0; i < NMOM; ++i) {
        float v = a[i];
        #pragma unroll
        for (int off = 32; off > 0; off >>= 1)
            v += __shfl_down(v, off, 64);
        a[i] = v;
    }

    // block reduce: lane0 of each of 4 waves -> LDS -> 15 atomics/block
    __shared__ float bl[4][NMOM];
    const int lane = threadIdx.x & 63;
    const int wid  = threadIdx.x >> 6;
    if (lane == 0) {
        #pragma unroll
        for (int i = 0; i < NMOM; ++i) bl[wid][i] = a[i];
    }
    __syncthreads();
    if (threadIdx.x < NMOM) {
        const int i = threadIdx.x;
        atomicAdd(&ws[i], bl[0][i] + bl[1][i] + bl[2][i] + bl[3][i]);
    }
}

// ---------------- Pass 2: LDS-staged compute -------------------------------
__global__ __launch_bounds__(256) void vfe_out(
    const float* __restrict__ x, const int* __restrict__ vnp,
    const float* __restrict__ W, const float* __restrict__ b,
    const float* __restrict__ gamma, const float* __restrict__ beta,
    const float* __restrict__ ws, float* __restrict__ out, int M)
{
    __shared__ float4 sx[32 * MAX_POINTS];        // 16 KB: 32 voxels
    const int lane = threadIdx.x & 63;            // channel
    const int wid  = threadIdx.x >> 6;

    // Per-lane BN affine from the 15 moments
    const float4 w4  = ((const float4*)W)[lane];
    const float bias = b[lane];
    const float cnt  = ws[14];
    const float nv   = fmaxf(cnt, 1.0f);
    const float wdots = w4.x*ws[0] + w4.y*ws[1] + w4.z*ws[2] + w4.w*ws[3];
    const float S    = wdots + cnt * bias;        // sum of h over valid
    const float mu   = S / nv;
    // w^T M2 w
    const float q2 = ws[4]*w4.x*w4.x + ws[8]*w4.y*w4.y + ws[11]*w4.z*w4.z + ws[13]*w4.w*w4.w
                   + 2.f*(ws[5]*w4.x*w4.y + ws[6]*w4.x*w4.z + ws[7]*w4.x*w4.w
                        + ws[9]*w4.y*w4.z + ws[10]*w4.y*w4.w + ws[12]*w4.z*w4.w);
    const float SS  = q2 + 2.f*bias*wdots + cnt*bias*bias;  // sum of h^2
    const float var = fmaxf(SS / nv - mu * mu, 0.f);
    const float A   = gamma[lane] * rsqrtf(var + EPS);
    const float B   = fmaf(-mu, A, beta[lane]);

    const int m0 = blockIdx.x * 32;               // 32 voxels per block

    // Stage 32 voxels (1024 float4) coalesced: 4 per thread
    const float4* __restrict__ xq = (const float4*)x + (size_t)m0 * MAX_POINTS;
    const int limit = min(1024, (M - m0) * MAX_POINTS);
    for (int t = threadIdx.x; t < limit; t += 256) sx[t] = xq[t];
    __syncthreads();

    // Each wave computes 8 voxels; lane = output channel
    #pragma unroll
    for (int v = 0; v < 8; ++v) {
        const int mv = wid * 8 + v;               // local voxel
        const int m  = m0 + mv;
        if (m >= M) break;
        const int n = vnp[m];                     // wave-uniform
        const float4* __restrict__ q = &sx[mv * MAX_POINTS];
        float acc = 0.f;
        #pragma unroll 4
        for (int p = 0; p < n; ++p) {
            const float4 pt = q[p];               // LDS same-addr broadcast
            const float h = fmaf(pt.x, w4.x, fmaf(pt.y, w4.y,
                            fmaf(pt.z, w4.z, fmaf(pt.w, w4.w, bias))));
            acc += fmaxf(fmaf(h, A, B), 0.f);
        }
        out[(size_t)m * C_OUT + lane] = acc / fmaxf((float)n, 1.0f);
    }
}

extern "C" void kernel_launch(void* const* d_in, const int* in_sizes, int n_in,
                              void* d_out, int out_size, void* d_ws, size_t ws_size,
                              hipStream_t stream) {
    const float* x     = (const float*)d_in[0];
    const int*   vnp   = (const int*)  d_in[1];
    const float* W     = (const float*)d_in[2];
    const float* b     = (const float*)d_in[3];
    const float* gamma = (const float*)d_in[4];
    const float* beta  = (const float*)d_in[5];
    float* out = (float*)d_out;
    float* ws  = (float*)d_ws;
    const int M = in_sizes[1];                    // 40000 voxels

    hipMemsetAsync(d_ws, 0, NMOM * sizeof(float), stream);
    vfe_stats<<<256, 256, 0, stream>>>(x, vnp, ws, M);
    const int nblk = (M + 31) / 32;
    vfe_out<<<nblk, 256, 0, stream>>>(x, vnp, W, b, gamma, beta, ws, out, M);
}